// Round 2
// baseline (87.426 us; speedup 1.0000x reference)
//
#include <hip/hip_runtime.h>
#include <hip/hip_bf16.h>
#include <stdint.h>

// out[n,f,i,j] = sum_k W[f,k]*patch[n,i,j,k] - 0.5||W_f||^2 - 0.5||X_{n,i,j}||^2
// x: (32,128,28,28) f32 ; W: (128,128,3,3) f32 ; out: (32,128,30,30) f32
// pad=2, ho=wo=30, L=28800, K=1152, F=128

#define N_IMG 32
#define C_IN 128
#define H_IN 28
#define HP 32
#define HO 30
#define P_SP (HO*HO)       // 900
#define L_TOT (P_SP*N_IMG) // 28800
#define F_OUT 128
#define K_TOT 1152

#define BLT 128            // GEMM block L-tile
#define TILES_L (L_TOT/BLT) // 225
#define SPLITK 3           // K split: 3 window-rows (rr) per block

typedef __attribute__((ext_vector_type(8))) short bf16x8;
typedef __attribute__((ext_vector_type(4))) float f32x4;

__device__ __forceinline__ unsigned short f2bf(float f) {
  union { float f; unsigned u; } t; t.f = f;
  unsigned r = t.u + 0x7fffu + ((t.u >> 16) & 1u);
  return (unsigned short)(r >> 16);
}

// ---------------------------------------------------------------------------
// Kernel 1: fused prep. Blocks 0..1023: pad+convert x -> channels-last bf16
// xcl[n][hp][wp][c] + per-pixel squared channel sums s[n][hp][wp].
// Blocks 1024..1151: W -> bf16 with K reordered (k' = rr*128+ch) + wnorm.
// ---------------------------------------------------------------------------
__global__ void prep_xw_kernel(const float* __restrict__ x,
                               const float* __restrict__ W,
                               unsigned short* __restrict__ xcl,
                               float* __restrict__ s,
                               unsigned short* __restrict__ Wbf,
                               float* __restrict__ wnorm) {
  int bid = blockIdx.x;
  if (bid < N_IMG * HP) {
    int n = bid >> 5, hp = bid & 31;
    __shared__ float row[C_IN * H_IN];   // 14336 B
    bool interior = (hp >= 2 && hp < 2 + H_IN);
    int h = hp - 2;
    if (interior) {
      for (int idx = threadIdx.x; idx < C_IN * H_IN; idx += 256) {
        int c = idx / H_IN, w = idx % H_IN;
        row[c * H_IN + w] = x[((n * C_IN + c) * H_IN + h) * H_IN + w];
      }
    }
    __syncthreads();
    for (int idx = threadIdx.x; idx < HP * C_IN; idx += 256) {
      int wp = idx >> 7, c = idx & 127;
      float v = 0.f;
      if (interior && wp >= 2 && wp < 2 + H_IN) v = row[c * H_IN + (wp - 2)];
      xcl[((n * HP + hp) * HP + wp) * C_IN + c] = f2bf(v);
    }
    int wp = threadIdx.x >> 3, l8 = threadIdx.x & 7;
    float sum = 0.f;
    if (interior && wp >= 2 && wp < 2 + H_IN) {
      for (int c = l8; c < C_IN; c += 8) {
        float v = row[c * H_IN + (wp - 2)];
        sum += v * v;
      }
    }
    sum += __shfl_down(sum, 4, 8);
    sum += __shfl_down(sum, 2, 8);
    sum += __shfl_down(sum, 1, 8);
    if (l8 == 0) s[(n * HP + hp) * HP + wp] = sum;
  } else {
    int f = bid - N_IMG * HP;
    const float* Wf = W + f * K_TOT;
    float part = 0.f;
    for (int k = threadIdx.x; k < K_TOT; k += 256) {
      float v = Wf[k];                 // k = ch*9 + rr
      part += v * v;
      int ch = k / 9, rr = k % 9;
      Wbf[f * K_TOT + rr * 128 + ch] = f2bf(v);
    }
    __shared__ float red[256];
    red[threadIdx.x] = part;
    __syncthreads();
    for (int st = 128; st > 0; st >>= 1) {
      if (threadIdx.x < st) red[threadIdx.x] += red[threadIdx.x + st];
      __syncthreads();
    }
    if (threadIdx.x == 0) wnorm[f] = 0.5f * part + 0.5f * (red[0] - part) + 0.f * red[0],
                          wnorm[f] = 0.5f * red[0];
  }
}

// ---------------------------------------------------------------------------
// Kernel 2: init out[n,f,i,j] = -(wnorm[f] + 0.5*sum_{3x3} s). grid (32,30).
// Every output element is written -> GEMM can pure-atomicAdd on top.
// ---------------------------------------------------------------------------
__global__ void init_out_kernel(const float* __restrict__ s,
                                const float* __restrict__ wnorm,
                                float* __restrict__ out) {
  int n = blockIdx.x, i = blockIdx.y;
  __shared__ float xn[HO];
  __shared__ float wn[F_OUT];
  if (threadIdx.x < HO) {
    int j = threadIdx.x;
    const float* sn = s + n * (HP * HP);
    float acc = 0.f;
#pragma unroll
    for (int dh = 0; dh < 3; dh++)
#pragma unroll
      for (int dw = 0; dw < 3; dw++)
        acc += sn[(i + dh) * HP + (j + dw)];
    xn[j] = 0.5f * acc;
  }
  if (threadIdx.x < F_OUT) wn[threadIdx.x] = wnorm[threadIdx.x];
  __syncthreads();
  float* outn = out + n * (F_OUT * P_SP) + i * HO;
  for (int idx = threadIdx.x; idx < F_OUT * HO; idx += 256) {
    int f = idx / HO, j = idx % HO;
    outn[f * P_SP + j] = -(wn[f] + xn[j]);
  }
}

// ---------------------------------------------------------------------------
// Kernel 3: implicit-im2col GEMM, split-K=3, atomic accumulate.
// Block tile 128(F) x 128(L), BK=128 (one window position rr per step,
// 3 steps/block). 4 waves (2x2), each 64x64 (acc[4][4], 16x16x32 bf16 MFMA).
// LDS rows 256 B k-contiguous, XOR-swizzled byte ^= (row&7)<<4;
// global_load_lds(16B) with linear LDS dest + inverse-swizzled source.
// ---------------------------------------------------------------------------
__global__ __launch_bounds__(256, 2) void adder_gemm_kernel(
    const unsigned short* __restrict__ Wbf,
    const unsigned short* __restrict__ xcl,
    float* __restrict__ out) {
  __shared__ unsigned short A_lds[128 * 128];   // 32 KB
  __shared__ unsigned short B_lds[128 * 128];   // 32 KB

  int tid = threadIdx.x;
  int lane = tid & 63, wid = tid >> 6;
  int tile = blockIdx.x % TILES_L;
  int split = blockIdx.x / TILES_L;
  int L0 = tile * BLT;

  const char* WbfB = (const char*)Wbf;
  const char* xclB = (const char*)xcl;
  char* AB = (char*)A_lds;
  char* BB = (char*)B_lds;

  int a_goff[8], b_goff[8], loff[8];
#pragma unroll
  for (int a = 0; a < 8; a++) {
    int q = a * 4 + wid;                 // 1KB chunk id, 32 chunks
    int row = q * 4 + (lane >> 4);       // row in tile (0..127)
    int b = (lane & 15) * 16;            // byte-in-row written
    int kb = b ^ ((row & 7) << 4);       // logical k-byte living there
    a_goff[a] = row * (K_TOT * 2) + kb;  // + rr*256 per step
    loff[a] = q * 1024 + lane * 16;      // linear LDS byte offset
    int l = L0 + row;
    int n = l / P_SP, p = l % P_SP, i = p / HO, j = p % HO;
    b_goff[a] = ((n * HP + i) * HP + j) * (C_IN * 2) + kb; // + (dh*32+dw)*256
  }

  f32x4 acc[4][4];
#pragma unroll
  for (int mi = 0; mi < 4; mi++)
#pragma unroll
    for (int ni = 0; ni < 4; ni++)
      acc[mi][ni] = (f32x4){0.f, 0.f, 0.f, 0.f};

  int wr = wid >> 1, wc = wid & 1;

  for (int t = 0; t < 3; t++) {
    int rr = split * 3 + t;
    int dh = rr / 3, dw = rr % 3;
    int woffA = rr * 256;
    int woffB = (dh * HP + dw) * (C_IN * 2);
#pragma unroll
    for (int a = 0; a < 8; a++)
      __builtin_amdgcn_global_load_lds(
          (const __attribute__((address_space(1))) void*)(WbfB + a_goff[a] + woffA),
          (__attribute__((address_space(3))) void*)(AB + loff[a]), 16, 0, 0);
#pragma unroll
    for (int a = 0; a < 8; a++)
      __builtin_amdgcn_global_load_lds(
          (const __attribute__((address_space(1))) void*)(xclB + b_goff[a] + woffB),
          (__attribute__((address_space(3))) void*)(BB + loff[a]), 16, 0, 0);
    __syncthreads();

#pragma unroll
    for (int kc = 0; kc < 4; kc++) {
      int kbl = kc * 64 + (lane >> 4) * 16;
      bf16x8 af[4], bfr[4];
#pragma unroll
      for (int mi = 0; mi < 4; mi++) {
        int rowf = wr * 64 + mi * 16 + (lane & 15);
        af[mi] = *(const bf16x8*)(AB + rowf * 256 + (kbl ^ ((rowf & 7) << 4)));
      }
#pragma unroll
      for (int ni = 0; ni < 4; ni++) {
        int cc = wc * 64 + ni * 16 + (lane & 15);
        bfr[ni] = *(const bf16x8*)(BB + cc * 256 + (kbl ^ ((cc & 7) << 4)));
      }
#pragma unroll
      for (int mi = 0; mi < 4; mi++)
#pragma unroll
        for (int ni = 0; ni < 4; ni++)
          acc[mi][ni] = __builtin_amdgcn_mfma_f32_16x16x32_bf16(
              af[mi], bfr[ni], acc[mi][ni], 0, 0, 0);
    }
    __syncthreads();
  }

  // Epilogue: pure atomic accumulation (out pre-initialized with -norms).
  // C/D layout: col = lane&15, row = (lane>>4)*4 + r
#pragma unroll
  for (int ni = 0; ni < 4; ni++) {
    int cc = wc * 64 + ni * 16 + (lane & 15);
    int l = L0 + cc;
    int n = l / P_SP, p = l % P_SP;
    float* outnp = out + n * (F_OUT * P_SP) + p;
#pragma unroll
    for (int mi = 0; mi < 4; mi++) {
      int f0 = wr * 64 + mi * 16 + (lane >> 4) * 4;
#pragma unroll
      for (int r = 0; r < 4; r++) {
        unsafeAtomicAdd(outnp + (f0 + r) * P_SP, acc[mi][ni][r]);
      }
    }
  }
}

// ---------------------------------------------------------------------------
extern "C" void kernel_launch(void* const* d_in, const int* in_sizes, int n_in,
                              void* d_out, int out_size, void* d_ws, size_t ws_size,
                              hipStream_t stream) {
  const float* x = (const float*)d_in[0];
  const float* W = (const float*)d_in[1];
  float* out = (float*)d_out;

  char* ws = (char*)d_ws;
  unsigned short* xcl = (unsigned short*)(ws);                   // 8,388,608 B
  unsigned short* Wbf = (unsigned short*)(ws + 8388608);         //   294,912 B
  float* wnorm = (float*)(ws + 8683520);                         //       512 B
  float* s     = (float*)(ws + 8684032);                         //   131,072 B
  // total ~8.82 MB

  prep_xw_kernel<<<N_IMG * HP + F_OUT, 256, 0, stream>>>(x, W, xcl, s, Wbf, wnorm);
  init_out_kernel<<<dim3(N_IMG, HO), 256, 0, stream>>>(s, wnorm, out);
  adder_gemm_kernel<<<TILES_L * SPLITK, 256, 0, stream>>>(Wbf, xcl, out);
}

// Round 3
// 36.095 us; speedup vs baseline: 2.4221x; 2.4221x over previous
//
#include <hip/hip_runtime.h>
#include <hip/hip_bf16.h>
#include <stdint.h>

// out[n,f,i,j] = sum_k W[f,k]*patch[n,i,j,k] - 0.5||W_f||^2 - 0.5||X_{n,i,j}||^2
// x: (32,128,28,28) f32 ; W: (128,128,3,3) f32 ; out: (32,128,30,30) f32
// pad=2, ho=wo=30, L=28800, K=1152, F=128

#define N_IMG 32
#define C_IN 128
#define H_IN 28
#define HP 32
#define HO 30
#define P_SP (HO*HO)       // 900
#define L_TOT (P_SP*N_IMG) // 28800
#define F_OUT 128
#define K_TOT 1152

#define BLT 64             // GEMM block L-tile
#define NBLK (L_TOT/BLT)   // 450 blocks (~1.76/CU, 3 co-resident via 48KB LDS)
#define NSTEP 18           // K split into 18 steps of BK=64 (9 window pos x 2 halves)

typedef __attribute__((ext_vector_type(8))) short bf16x8;
typedef __attribute__((ext_vector_type(4))) float f32x4;

__device__ __forceinline__ unsigned short f2bf(float f) {
  union { float f; unsigned u; } t; t.f = f;
  unsigned r = t.u + 0x7fffu + ((t.u >> 16) & 1u);
  return (unsigned short)(r >> 16);
}

// ---------------------------------------------------------------------------
// Kernel 1: fused prep. Blocks 0..1023: pad+convert x -> channels-last bf16
// xcl[n][hp][wp][c] + per-pixel squared channel sums s[n][hp][wp] (all pixels
// written, zero in padding). Blocks 1024..1151: W -> bf16 reordered
// (k' = rr*128+ch) + wnorm[f] = 0.5||W_f||^2.
// ---------------------------------------------------------------------------
__global__ void prep_xw_kernel(const float* __restrict__ x,
                               const float* __restrict__ W,
                               unsigned short* __restrict__ xcl,
                               float* __restrict__ s,
                               unsigned short* __restrict__ Wbf,
                               float* __restrict__ wnorm) {
  int bid = blockIdx.x;
  if (bid < N_IMG * HP) {
    int n = bid >> 5, hp = bid & 31;
    __shared__ float row[C_IN * H_IN];   // 14336 B
    bool interior = (hp >= 2 && hp < 2 + H_IN);
    int h = hp - 2;
    if (interior) {
      for (int idx = threadIdx.x; idx < C_IN * H_IN; idx += 256) {
        int c = idx / H_IN, w = idx % H_IN;
        row[c * H_IN + w] = x[((n * C_IN + c) * H_IN + h) * H_IN + w];
      }
    }
    __syncthreads();
    for (int idx = threadIdx.x; idx < HP * C_IN; idx += 256) {
      int wp = idx >> 7, c = idx & 127;
      float v = 0.f;
      if (interior && wp >= 2 && wp < 2 + H_IN) v = row[c * H_IN + (wp - 2)];
      xcl[((n * HP + hp) * HP + wp) * C_IN + c] = f2bf(v);
    }
    int wp = threadIdx.x >> 3, l8 = threadIdx.x & 7;
    float sum = 0.f;
    if (interior && wp >= 2 && wp < 2 + H_IN) {
      for (int c = l8; c < C_IN; c += 8) {
        float v = row[c * H_IN + (wp - 2)];
        sum += v * v;
      }
    }
    sum += __shfl_down(sum, 4, 8);
    sum += __shfl_down(sum, 2, 8);
    sum += __shfl_down(sum, 1, 8);
    if (l8 == 0) s[(n * HP + hp) * HP + wp] = sum;
  } else {
    int f = bid - N_IMG * HP;
    const float* Wf = W + f * K_TOT;
    float part = 0.f;
    for (int k = threadIdx.x; k < K_TOT; k += 256) {
      float v = Wf[k];                 // k = ch*9 + rr
      part += v * v;
      int ch = k / 9, rr = k % 9;
      Wbf[f * K_TOT + rr * 128 + ch] = f2bf(v);
    }
    __shared__ float red[256];
    red[threadIdx.x] = part;
    __syncthreads();
    for (int st = 128; st > 0; st >>= 1) {
      if (threadIdx.x < st) red[threadIdx.x] += red[threadIdx.x + st];
      __syncthreads();
    }
    if (threadIdx.x == 0) wnorm[f] = 0.5f * red[0];
  }
}

// ---------------------------------------------------------------------------
// Kernel 2: implicit-im2col GEMM, prefetch-double-buffered (T3-minimum).
// Block tile 128(F) x 64(L), BK=64, 18 K-steps. 4 waves (2x2), each 64x32.
// LDS rows 128 B k-contiguous, XOR-swizzled byte ^= (row&7)<<4 (involution,
// applied on BOTH the global source and the ds_read — linear LDS dest so
// global_load_lds(16B) works). Double-buffered: A 2x16KB + B 2x8KB = 48KB.
// Schedule per step: STAGE(t+1) -> ds_read+MFMA(t) -> syncthreads (single
// vmcnt(0)+lgkmcnt(0) drain per step; stage latency hides under compute).
// Epilogue: fused -wnorm[f] -0.5*sum3x3(s) and direct stores (no atomics).
// ---------------------------------------------------------------------------
__global__ __launch_bounds__(256, 3) void adder_gemm_kernel(
    const unsigned short* __restrict__ Wbf,
    const unsigned short* __restrict__ xcl,
    const float* __restrict__ wnorm,
    const float* __restrict__ s,
    float* __restrict__ out) {
  __shared__ unsigned short A_lds[2][128 * 64];   // 2 x 16 KB
  __shared__ unsigned short B_lds[2][64 * 64];    // 2 x 8 KB
  __shared__ float wn_s[F_OUT];

  int tid = threadIdx.x;
  int lane = tid & 63, wid = tid >> 6;
  int L0 = blockIdx.x * BLT;

  const char* WbfB = (const char*)Wbf;
  const char* xclB = (const char*)xcl;

  // --- staging addresses ---
  // Chunk = 1KB = 8 rows x 128B, one wave per chunk-issue. row&7 == lane>>3.
  // Physical LDS [row][b] holds logical k-byte (b ^ ((row&7)<<4)).
  int kb = ((lane & 7) * 16) ^ ((lane >> 3) << 4);   // pre-swizzled source byte
  int lds_off = wid * 1024 + lane * 16;              // linear dest within issue
  int a_goff[4];
#pragma unroll
  for (int a = 0; a < 4; a++) {
    int rowf = a * 32 + wid * 8 + (lane >> 3);       // 0..127
    a_goff[a] = rowf * (K_TOT * 2) + kb;             // + rr*256 + half*128 per step
  }
  int b_goff[2];
#pragma unroll
  for (int a = 0; a < 2; a++) {
    int cc = a * 32 + wid * 8 + (lane >> 3);         // 0..63
    int l = L0 + cc;
    int n = l / P_SP, p = l % P_SP, i = p / HO, j = p % HO;
    b_goff[a] = ((n * HP + i) * HP + j) * (C_IN * 2) + kb; // + (dh*32+dw)*256 + half*128
  }

  auto STAGE = [&](int t, int bufi) {
    int rr = t >> 1, half = t & 1;
    int woffA = rr * 256 + half * 128;
    int woffB = ((rr / 3) * HP + (rr % 3)) * (C_IN * 2) + half * 128;
    char* AB = (char*)(&A_lds[bufi][0]);
    char* BB = (char*)(&B_lds[bufi][0]);
#pragma unroll
    for (int a = 0; a < 4; a++)
      __builtin_amdgcn_global_load_lds(
          (const __attribute__((address_space(1))) void*)(WbfB + a_goff[a] + woffA),
          (__attribute__((address_space(3))) void*)(AB + a * 4096 + lds_off), 16, 0, 0);
#pragma unroll
    for (int a = 0; a < 2; a++)
      __builtin_amdgcn_global_load_lds(
          (const __attribute__((address_space(1))) void*)(xclB + b_goff[a] + woffB),
          (__attribute__((address_space(3))) void*)(BB + a * 4096 + lds_off), 16, 0, 0);
  };

  f32x4 acc[4][2];
#pragma unroll
  for (int mi = 0; mi < 4; mi++)
#pragma unroll
    for (int ni = 0; ni < 2; ni++)
      acc[mi][ni] = (f32x4){0.f, 0.f, 0.f, 0.f};

  int wr = wid >> 1, wc = wid & 1;

  // prologue: stage step 0 into buf 0, load wnorm to LDS
  STAGE(0, 0);
  if (tid < F_OUT) wn_s[tid] = wnorm[tid];
  __syncthreads();   // drains vmcnt(0): buf0 ready

  for (int t = 0; t < NSTEP; t++) {
    int cur = t & 1;
    if (t + 1 < NSTEP) STAGE(t + 1, cur ^ 1);   // prefetch next (other buffer)

    const char* AB = (const char*)(&A_lds[cur][0]);
    const char* BB = (const char*)(&B_lds[cur][0]);
#pragma unroll
    for (int kc = 0; kc < 2; kc++) {
      int kbl = kc * 64 + (lane >> 4) * 16;
      bf16x8 af[4], bfr[2];
#pragma unroll
      for (int mi = 0; mi < 4; mi++) {
        int rowf = wr * 64 + mi * 16 + (lane & 15);
        af[mi] = *(const bf16x8*)(AB + rowf * 128 + (kbl ^ ((rowf & 7) << 4)));
      }
#pragma unroll
      for (int ni = 0; ni < 2; ni++) {
        int cc = wc * 32 + ni * 16 + (lane & 15);
        bfr[ni] = *(const bf16x8*)(BB + cc * 128 + (kbl ^ ((cc & 7) << 4)));
      }
#pragma unroll
      for (int mi = 0; mi < 4; mi++)
#pragma unroll
        for (int ni = 0; ni < 2; ni++)
          acc[mi][ni] = __builtin_amdgcn_mfma_f32_16x16x32_bf16(
              af[mi], bfr[ni], acc[mi][ni], 0, 0, 0);
    }
    __syncthreads();   // one vmcnt(0)+lgkmcnt(0) drain per step: next buf ready,
                       // and this buf safe to overwrite next iteration
  }

  // Epilogue: fused norms, direct stores. C/D: col=lane&15, row=(lane>>4)*4+r
#pragma unroll
  for (int ni = 0; ni < 2; ni++) {
    int cc = wc * 32 + ni * 16 + (lane & 15);
    int l = L0 + cc;
    int n = l / P_SP, p = l % P_SP, i = p / HO, j = p % HO;
    const float* sn = s + n * (HP * HP);
    float xn = 0.f;
#pragma unroll
    for (int dh = 0; dh < 3; dh++)
#pragma unroll
      for (int dw = 0; dw < 3; dw++)
        xn += sn[(i + dh) * HP + (j + dw)];
    xn *= 0.5f;
    float* outnp = out + n * (F_OUT * P_SP) + p;
#pragma unroll
    for (int mi = 0; mi < 4; mi++) {
      int f0 = wr * 64 + mi * 16 + (lane >> 4) * 4;
#pragma unroll
      for (int r = 0; r < 4; r++) {
        int f = f0 + r;
        outnp[f * P_SP] = acc[mi][ni][r] - wn_s[f] - xn;
      }
    }
  }
}

// ---------------------------------------------------------------------------
extern "C" void kernel_launch(void* const* d_in, const int* in_sizes, int n_in,
                              void* d_out, int out_size, void* d_ws, size_t ws_size,
                              hipStream_t stream) {
  const float* x = (const float*)d_in[0];
  const float* W = (const float*)d_in[1];
  float* out = (float*)d_out;

  char* ws = (char*)d_ws;
  unsigned short* xcl = (unsigned short*)(ws);                   // 8,388,608 B
  unsigned short* Wbf = (unsigned short*)(ws + 8388608);         //   294,912 B
  float* wnorm = (float*)(ws + 8683520);                         //       512 B
  float* s     = (float*)(ws + 8684032);                         //   131,072 B

  prep_xw_kernel<<<N_IMG * HP + F_OUT, 256, 0, stream>>>(x, W, xcl, s, Wbf, wnorm);
  adder_gemm_kernel<<<NBLK, 256, 0, stream>>>(Wbf, xcl, wnorm, s, out);
}

// Round 4
// 31.409 us; speedup vs baseline: 2.7835x; 1.1492x over previous
//
#include <hip/hip_runtime.h>
#include <hip/hip_bf16.h>
#include <stdint.h>

// out[n,f,i,j] = sum_k W[f,k]*patch[n,i,j,k] - 0.5||W_f||^2 - 0.5||X_{n,i,j}||^2
// x: (32,128,28,28) f32 ; W: (128,128,3,3) f32 ; out: (32,128,30,30) f32
// pad=2, ho=wo=30, L=28800, K=1152, F=128

#define N_IMG 32
#define C_IN 128
#define H_IN 28
#define HP 32
#define HO 30
#define P_SP (HO*HO)       // 900
#define L_TOT (P_SP*N_IMG) // 28800
#define F_OUT 128
#define K_TOT 1152

#define BLT 64             // GEMM block L-tile
#define NBLK (L_TOT/BLT)   // 450 blocks, 72KB LDS -> 2 blocks/CU
#define NSTEP 18           // 18 K-steps of BK=64 (9 window pos x 2 halves)

typedef __attribute__((ext_vector_type(8))) short bf16x8;
typedef __attribute__((ext_vector_type(8))) unsigned short u16x8;
typedef __attribute__((ext_vector_type(4))) float f32x4;

__device__ __forceinline__ unsigned short f2bf(float f) {
  union { float f; unsigned u; } t; t.f = f;
  unsigned r = t.u + 0x7fffu + ((t.u >> 16) & 1u);
  return (unsigned short)(r >> 16);
}

// ---------------------------------------------------------------------------
// Kernel 1: fused prep. Blocks 0..1023: pad+convert x -> channels-last bf16
// xcl[n][hp][wp][c] (u16x8 stores) + per-pixel squared sums s[n][hp][wp].
// Blocks 1024..1151: W -> bf16 reordered (k' = rr*128+ch) + wnorm.
// ---------------------------------------------------------------------------
__global__ void prep_xw_kernel(const float* __restrict__ x,
                               const float* __restrict__ W,
                               unsigned short* __restrict__ xcl,
                               float* __restrict__ s,
                               unsigned short* __restrict__ Wbf,
                               float* __restrict__ wnorm) {
  int bid = blockIdx.x;
  if (bid < N_IMG * HP) {
    int n = bid >> 5, hp = bid & 31;
    __shared__ float rowT[H_IN * C_IN];   // [w][c], 14336 B
    bool interior = (hp >= 2 && hp < 2 + H_IN);
    int h = hp - 2;
    if (interior) {
      // float4 reads: x[n][c][h][w4*4..+3] -> LDS transposed [w][c]
      for (int idx = threadIdx.x; idx < C_IN * 7; idx += 256) {
        int c = idx / 7, w4 = (idx - c * 7) * 4;
        const float* xp = x + ((n * C_IN + c) * H_IN + h) * H_IN + w4;
        float4 v = *(const float4*)xp;
        rowT[(w4 + 0) * C_IN + c] = v.x;
        rowT[(w4 + 1) * C_IN + c] = v.y;
        rowT[(w4 + 2) * C_IN + c] = v.z;
        rowT[(w4 + 3) * C_IN + c] = v.w;
      }
    }
    __syncthreads();
    // xcl: 512 x 16B stores (zero in padding)
    for (int idx = threadIdx.x; idx < HP * 16; idx += 256) {
      int wp = idx >> 4, c8 = (idx & 15) * 8;
      u16x8 o;
#pragma unroll
      for (int q = 0; q < 8; q++) o[q] = 0;
      if (interior && wp >= 2 && wp < 2 + H_IN) {
        const float* rp = &rowT[(wp - 2) * C_IN + c8];
#pragma unroll
        for (int q = 0; q < 8; q++) o[q] = (short)f2bf(rp[q]);
      }
      *(u16x8*)(&xcl[((n * HP + hp) * HP + wp) * C_IN + c8]) = o;
    }
    // squared channel sums: 8 threads per wp
    int wp = threadIdx.x >> 3, l8 = threadIdx.x & 7;
    float sum = 0.f;
    if (interior && wp >= 2 && wp < 2 + H_IN) {
      const float* rp = &rowT[(wp - 2) * C_IN];
      for (int c = l8; c < C_IN; c += 8) { float v = rp[c]; sum += v * v; }
    }
    sum += __shfl_down(sum, 4, 8);
    sum += __shfl_down(sum, 2, 8);
    sum += __shfl_down(sum, 1, 8);
    if (l8 == 0) s[(n * HP + hp) * HP + wp] = sum;
  } else {
    int f = bid - N_IMG * HP;
    const float* Wf = W + f * K_TOT;
    float part = 0.f;
    for (int k = threadIdx.x; k < K_TOT; k += 256) {
      float v = Wf[k];                 // k = ch*9 + rr
      part += v * v;
      int ch = k / 9, rr = k % 9;
      Wbf[f * K_TOT + rr * 128 + ch] = f2bf(v);
    }
    __shared__ float red[256];
    red[threadIdx.x] = part;
    __syncthreads();
    for (int st = 128; st > 0; st >>= 1) {
      if (threadIdx.x < st) red[threadIdx.x] += red[threadIdx.x + st];
      __syncthreads();
    }
    if (threadIdx.x == 0) wnorm[f] = 0.5f * red[0];
  }
}

// ---------------------------------------------------------------------------
// Kernel 2: implicit-im2col GEMM, TRIPLE-buffered, counted-vmcnt pipeline
// (T3/T4): STAGE(t+2) issued each step; s_waitcnt vmcnt(6) (never 0 in the
// main loop) + raw s_barrier. Safety: STAGE(t+2) writes the buffer last read
// at step t-1; all step-t-1 ds_reads completed before that step's barrier
// (MFMA operand consumption forces lgkm drain before the wave's last MFMA).
// Block tile 128(F) x 64(L), BK=64. 4 waves (2x2), each 64x32.
// LDS rows 128 B k-contiguous, XOR-swizzled byte ^= (row&7)<<4, applied as
// inverse-swizzled GLOBAL source + swizzled ds_read (linear LDS dest).
// Epilogue: acc -> LDS (padded 65-col) -> coalesced 256B output stores.
// ---------------------------------------------------------------------------
__global__ __launch_bounds__(256, 2) void adder_gemm_kernel(
    const unsigned short* __restrict__ Wbf,
    const unsigned short* __restrict__ xcl,
    const float* __restrict__ wnorm,
    const float* __restrict__ s,
    float* __restrict__ out) {
  __shared__ unsigned short A_lds[3][128 * 64];   // 3 x 16 KB
  __shared__ unsigned short B_lds[3][64 * 64];    // 3 x 8 KB
  __shared__ float wn_s[F_OUT];
  __shared__ float xn_s[BLT];

  int tid = threadIdx.x;
  int lane = tid & 63, wid = tid >> 6;
  int L0 = blockIdx.x * BLT;

  const char* WbfB = (const char*)Wbf;
  const char* xclB = (const char*)xcl;

  // Staging addresses. Chunk = 1KB = 8 rows x 128B. row&7 == lane>>3.
  // Physical LDS [row][b] holds logical k-byte (b ^ ((row&7)<<4)).
  int kb = ((lane & 7) * 16) ^ ((lane >> 3) << 4);   // pre-swizzled source byte
  int lds_off = wid * 1024 + lane * 16;              // linear dest within issue
  int a_goff[4];
#pragma unroll
  for (int a = 0; a < 4; a++) {
    int rowf = a * 32 + wid * 8 + (lane >> 3);       // 0..127
    a_goff[a] = rowf * (K_TOT * 2) + kb;             // + rr*256 + half*128
  }
  int b_goff[2];
#pragma unroll
  for (int a = 0; a < 2; a++) {
    int cc = a * 32 + wid * 8 + (lane >> 3);         // 0..63
    int l = L0 + cc;
    int n = l / P_SP, p = l % P_SP, i = p / HO, j = p % HO;
    b_goff[a] = ((n * HP + i) * HP + j) * (C_IN * 2) + kb; // + (dh*32+dw)*256 + half*128
  }

  auto STAGE = [&](int t, int bufi) {
    int rr = t >> 1, half = t & 1;
    int woffA = rr * 256 + half * 128;
    int woffB = ((rr / 3) * HP + (rr % 3)) * (C_IN * 2) + half * 128;
    char* AB = (char*)(&A_lds[bufi][0]);
    char* BB = (char*)(&B_lds[bufi][0]);
#pragma unroll
    for (int a = 0; a < 4; a++)
      __builtin_amdgcn_global_load_lds(
          (const __attribute__((address_space(1))) void*)(WbfB + a_goff[a] + woffA),
          (__attribute__((address_space(3))) void*)(AB + a * 4096 + lds_off), 16, 0, 0);
#pragma unroll
    for (int a = 0; a < 2; a++)
      __builtin_amdgcn_global_load_lds(
          (const __attribute__((address_space(1))) void*)(xclB + b_goff[a] + woffB),
          (__attribute__((address_space(3))) void*)(BB + a * 4096 + lds_off), 16, 0, 0);
  };

  f32x4 acc[4][2];
#pragma unroll
  for (int mi = 0; mi < 4; mi++)
#pragma unroll
    for (int ni = 0; ni < 2; ni++)
      acc[mi][ni] = (f32x4){0.f, 0.f, 0.f, 0.f};

  int wr = wid >> 1, wc = wid & 1;

  // Prologue: prefetch steps 0 and 1; wait for step 0 only.
  STAGE(0, 0);
  STAGE(1, 1);
  if (tid < F_OUT) wn_s[tid] = wnorm[tid];
  asm volatile("s_waitcnt vmcnt(6)" ::: "memory");
  __builtin_amdgcn_s_barrier();

#pragma unroll
  for (int t = 0; t < NSTEP; t++) {
    int cur = t % 3;
    if (t + 2 < NSTEP) STAGE(t + 2, (t + 2) % 3);

    const char* AB = (const char*)(&A_lds[cur][0]);
    const char* BB = (const char*)(&B_lds[cur][0]);
#pragma unroll
    for (int kc = 0; kc < 2; kc++) {
      int kbl = kc * 64 + (lane >> 4) * 16;
      bf16x8 af[4], bfr[2];
#pragma unroll
      for (int mi = 0; mi < 4; mi++) {
        int rowf = wr * 64 + mi * 16 + (lane & 15);
        af[mi] = *(const bf16x8*)(AB + rowf * 128 + (kbl ^ ((rowf & 7) << 4)));
      }
#pragma unroll
      for (int ni = 0; ni < 2; ni++) {
        int cc = wc * 32 + ni * 16 + (lane & 15);
        bfr[ni] = *(const bf16x8*)(BB + cc * 128 + (kbl ^ ((cc & 7) << 4)));
      }
      __builtin_amdgcn_s_setprio(1);
#pragma unroll
      for (int mi = 0; mi < 4; mi++)
#pragma unroll
        for (int ni = 0; ni < 2; ni++)
          acc[mi][ni] = __builtin_amdgcn_mfma_f32_16x16x32_bf16(
              af[mi], bfr[ni], acc[mi][ni], 0, 0, 0);
      __builtin_amdgcn_s_setprio(0);
    }
    // Counted wait: leave the just-issued STAGE(t+2) (6 loads) in flight;
    // guarantees STAGE(t+1) has landed. Drain fully only in the tail.
    if (t + 2 < NSTEP) asm volatile("s_waitcnt vmcnt(6)" ::: "memory");
    else               asm volatile("s_waitcnt vmcnt(0)" ::: "memory");
    __builtin_amdgcn_s_barrier();
  }

  // ---- Epilogue: fused norms + coalesced stores via LDS transpose ----
  float* Cst = (float*)(&A_lds[0][0]);   // 128 x 65 f32 = 33280 B (fits 48KB)
  if (tid < BLT) {
    int l = L0 + tid;
    int n = l / P_SP, p = l % P_SP, i = p / HO, j = p % HO;
    const float* sn = s + n * (HP * HP);
    float a9 = 0.f;
#pragma unroll
    for (int dh = 0; dh < 3; dh++)
#pragma unroll
      for (int dw = 0; dw < 3; dw++)
        a9 += sn[(i + dh) * HP + (j + dw)];
    xn_s[tid] = 0.5f * a9;
  }
  // dump acc: f = wr*64+mi*16+(lane>>4)*4+r ; cc = wc*32+ni*16+(lane&15)
#pragma unroll
  for (int mi = 0; mi < 4; mi++) {
    int f0 = wr * 64 + mi * 16 + (lane >> 4) * 4;
#pragma unroll
    for (int ni = 0; ni < 2; ni++) {
      int cc = wc * 32 + ni * 16 + (lane & 15);
#pragma unroll
      for (int r = 0; r < 4; r++)
        Cst[(f0 + r) * 65 + cc] = acc[mi][ni][r];
    }
  }
  __syncthreads();
  // coalesced stores: lane group = 64 consecutive columns for fixed f
  {
    int col = tid & 63, fgrp = tid >> 6;
    int l = L0 + col;
    int n = l / P_SP, p = l % P_SP;
    float* ob = out + n * (F_OUT * P_SP) + p;
    float xn = xn_s[col];
#pragma unroll
    for (int q = 0; q < 32; q++) {
      int f = fgrp * 32 + q;
      ob[f * P_SP] = Cst[f * 65 + col] - wn_s[f] - xn;
    }
  }
}

// ---------------------------------------------------------------------------
extern "C" void kernel_launch(void* const* d_in, const int* in_sizes, int n_in,
                              void* d_out, int out_size, void* d_ws, size_t ws_size,
                              hipStream_t stream) {
  const float* x = (const float*)d_in[0];
  const float* W = (const float*)d_in[1];
  float* out = (float*)d_out;

  char* ws = (char*)d_ws;
  unsigned short* xcl = (unsigned short*)(ws);                   // 8,388,608 B
  unsigned short* Wbf = (unsigned short*)(ws + 8388608);         //   294,912 B
  float* wnorm = (float*)(ws + 8683520);                         //       512 B
  float* s     = (float*)(ws + 8684032);                         //   131,072 B

  prep_xw_kernel<<<N_IMG * HP + F_OUT, 256, 0, stream>>>(x, W, xcl, s, Wbf, wnorm);
  adder_gemm_kernel<<<NBLK, 256, 0, stream>>>(Wbf, xcl, wnorm, s, out);
}

// Round 5
// 29.580 us; speedup vs baseline: 2.9556x; 1.0618x over previous
//
#include <hip/hip_runtime.h>
#include <hip/hip_bf16.h>
#include <stdint.h>

// out[n,f,i,j] = sum_k W[f,k]*patch[n,i,j,k] - 0.5||W_f||^2 - 0.5||X_{n,i,j}||^2
// x: (32,128,28,28) f32 ; W: (128,128,3,3) f32 ; out: (32,128,30,30) f32
// pad=2, ho=wo=30, L=28800, K=1152, F=128

#define N_IMG 32
#define C_IN 128
#define H_IN 28
#define HO 30
#define P_SP 900
#define F_OUT 128
#define K_TOT 1152

#define BLT 60              // L-tile: 60 cols = exactly 2 raster rows, no image crossing
#define TPI 15              // tiles per image (900/60)
#define NBLK (N_IMG*TPI)    // 480 blocks; 66KB LDS -> 2 blocks/CU (94% slot fill)
#define NSTEP 18            // K steps of BK=64 (9 window positions x 2 halves)

typedef __attribute__((ext_vector_type(8))) short bf16x8;
typedef __attribute__((ext_vector_type(4))) unsigned short u16x4;
typedef __attribute__((ext_vector_type(8))) unsigned short u16x8;
typedef __attribute__((ext_vector_type(4))) float f32x4;

__device__ __forceinline__ unsigned short f2bf(float f) {
  union { float f; unsigned u; } t; t.f = f;
  unsigned r = t.u + 0x7fffu + ((t.u >> 16) & 1u);
  return (unsigned short)(r >> 16);
}

// ---------------------------------------------------------------------------
// Kernel 1 (tiny): W -> bf16 reordered k' = rr*128 + ch, + wnorm = 0.5||W_f||^2
// ---------------------------------------------------------------------------
__global__ void prep_w_kernel(const float* __restrict__ W,
                              unsigned short* __restrict__ Wbf,
                              float* __restrict__ wnorm) {
  int f = blockIdx.x;
  const float* Wf = W + f * K_TOT;
  float part = 0.f;
  for (int k = threadIdx.x; k < K_TOT; k += 256) {
    float v = Wf[k];                 // k = ch*9 + rr
    part += v * v;
    int ch = k / 9, rr = k - ch * 9;
    Wbf[f * K_TOT + rr * 128 + ch] = f2bf(v);
  }
  __shared__ float red[256];
  red[threadIdx.x] = part;
  __syncthreads();
  for (int st = 128; st > 0; st >>= 1) {
    if (threadIdx.x < st) red[threadIdx.x] += red[threadIdx.x + st];
    __syncthreads();
  }
  if (threadIdx.x == 0) wnorm[f] = 0.5f * red[0];
}

// ---------------------------------------------------------------------------
// Kernel 2: fused x-prep + implicit-im2col GEMM.
// Per block: stage the x footprint (4 padded rows x 32 wp x 128 c) once into
// LDS as bf16 channels-last with XOR swizzle byte ^= ((pix&15)<<4); the
// K-loop streams ONLY A (Wbf, L2-hot 294KB shared by all blocks) through a
// double-buffered 16KB tile via global_load_lds (pre-swizzled source,
// ^((row&7)<<4) on 128-B rows). B fragments read directly from the footprint.
// xnorm computed in-LDS from per-pixel squared sums. 4 waves, wave = 64f x 32l
// (cols 60..63 dead: clamped reads, skipped stores).
// ---------------------------------------------------------------------------
__global__ __launch_bounds__(256, 2) void adder_fused_kernel(
    const float* __restrict__ x,
    const unsigned short* __restrict__ Wbf,
    const float* __restrict__ wnorm,
    float* __restrict__ out) {
  __shared__ unsigned short xfoot[128 * 128];   // 128 pix x 256 B = 32 KB
  __shared__ unsigned short A_lds[2][64 * 128]; // 2 x 16 KB (128 rows x 128 B)
  __shared__ float pixsum_s[128];
  __shared__ float xn_s[64];
  __shared__ float wn_s[F_OUT];

  int tid = threadIdx.x, lane = tid & 63, wid = tid >> 6;
  int bid = blockIdx.x;
  int n = bid / TPI, timg = bid - n * TPI;
  int i0 = timg * 2, p0 = timg * BLT;

  char* XF = (char*)xfoot;
  char* A0 = (char*)&A_lds[0][0];
  char* A1 = (char*)&A_lds[1][0];
  const char* WbfB = (const char*)Wbf;

  // ---- A staging addresses (chunk = 1KB = 8 rows x 128B) ----
  int kb = ((lane & 7) * 16) ^ ((lane >> 3) << 4);  // pre-swizzled source byte
  int a_goff[4];
#pragma unroll
  for (int a = 0; a < 4; a++) {
    int q = a * 4 + wid;                  // 0..15
    int rowf = q * 8 + (lane >> 3);       // 0..127
    a_goff[a] = rowf * (K_TOT * 2) + kb;  // + t*128 per K-step
  }
  int a_loff = wid * 1024 + lane * 16;

  auto STAGE = [&](int t, char* AB) {
    int off = t * 128;
#pragma unroll
    for (int a = 0; a < 4; a++)
      __builtin_amdgcn_global_load_lds(
          (const __attribute__((address_space(1))) void*)(WbfB + a_goff[a] + off),
          (__attribute__((address_space(3))) void*)(AB + a * 4096 + a_loff), 16, 0, 0);
  };

  // ---- prologue: kick off A(0) DMA, then convert x footprint into LDS ----
  STAGE(0, A0);
  if (tid < F_OUT) wn_s[tid] = wnorm[tid];

  // x conversion: 4 padded rows (hr = i0-2+r), wp = w+2, channels-last bf16.
  // u over [r(4)][w4(7)][cq(32)]: 4 float4 loads (c..c+3) -> 4 b64 ds_writes.
  for (int u = tid; u < 896; u += 256) {
    int r = u / 224, rem = u - r * 224;
    int w4 = rem >> 5, cq = rem & 31, c = cq * 4;
    int hr = i0 - 2 + r;
    float vv[4][4];
    if (hr >= 0 && hr < H_IN) {
#pragma unroll
      for (int q = 0; q < 4; q++) {
        float4 t4 = *(const float4*)(x + (((n * C_IN + c + q) * H_IN + hr) * H_IN + w4 * 4));
        vv[q][0] = t4.x; vv[q][1] = t4.y; vv[q][2] = t4.z; vv[q][3] = t4.w;
      }
    } else {
#pragma unroll
      for (int q = 0; q < 4; q++)
#pragma unroll
        for (int ws2 = 0; ws2 < 4; ws2++) vv[q][ws2] = 0.f;
    }
#pragma unroll
    for (int ws2 = 0; ws2 < 4; ws2++) {
      int wp = w4 * 4 + ws2 + 2;          // 2..29
      int pix = r * 32 + wp;
      u16x4 o;
#pragma unroll
      for (int q = 0; q < 4; q++) o[q] = f2bf(vv[q][ws2]);
      *(u16x4*)(XF + pix * 256 + ((c * 2) ^ ((pix & 15) << 4))) = o;
    }
  }
  // border zeros: wp in {0,1,30,31} for all 4 rows (16 pix x 256 B)
  {
    int r = tid >> 6, wi = (tid >> 4) & 3, slot = tid & 15;
    int wp = (wi < 2) ? wi : 28 + wi;     // 0,1,30,31
    int pix = r * 32 + wp;
    u16x8 z;
#pragma unroll
    for (int q = 0; q < 8; q++) z[q] = 0;
    *(u16x8*)(XF + pix * 256 + ((slot * 16) ^ ((pix & 15) << 4))) = z;
  }
  __syncthreads();

  // per-pixel squared channel sums (from bf16 x; err ~0.2 << threshold)
  {
    int pix = tid >> 1, ch = tid & 1;
    float ssum = 0.f;
#pragma unroll
    for (int q = 0; q < 8; q++) {
      u16x8 v8 = *(const u16x8*)(XF + pix * 256 + (((ch * 128) + q * 16) ^ ((pix & 15) << 4)));
#pragma unroll
      for (int e = 0; e < 8; e++) {
        union { unsigned u; float f; } cv; cv.u = ((unsigned)v8[e]) << 16;
        ssum += cv.f * cv.f;
      }
    }
    ssum += __shfl_xor(ssum, 1);
    if (!ch) pixsum_s[pix] = ssum;
  }
  __syncthreads();
  if (tid < BLT) {
    int il = tid / HO, j = tid - il * HO;
    float a9 = 0.f;
#pragma unroll
    for (int dh = 0; dh < 3; dh++)
#pragma unroll
      for (int dw = 0; dw < 3; dw++)
        a9 += pixsum_s[(il + dh) * 32 + (j + dw)];
    xn_s[tid] = 0.5f * a9;
  }
  __syncthreads();   // drains vmcnt: A(0) landed; xn_s/pixsum visible

  // ---- K-loop: stream A only; B comes from resident xfoot ----
  f32x4 acc[4][2];
#pragma unroll
  for (int mi = 0; mi < 4; mi++)
#pragma unroll
    for (int ni = 0; ni < 2; ni++)
      acc[mi][ni] = (f32x4){0.f, 0.f, 0.f, 0.f};

  int wr = wid >> 1, wc = wid & 1;
  int pix0[2];
#pragma unroll
  for (int ni = 0; ni < 2; ni++) {
    int cc = wc * 32 + ni * 16 + (lane & 15);
    if (cc > BLT - 1) cc = BLT - 1;       // dead cols clamp (results discarded)
    int il = cc / HO, j = cc - il * HO;
    pix0[ni] = il * 32 + j;
  }
  int kfrag = (lane >> 4) * 16;

#pragma unroll 2
  for (int t = 0; t < NSTEP; t++) {
    char* ABc = (t & 1) ? A1 : A0;
    char* ABn = (t & 1) ? A0 : A1;
    if (t + 1 < NSTEP) STAGE(t + 1, ABn);

    int rr = t >> 1, half = t & 1;
    int dh = rr / 3, dw = rr - 3 * dh;
    int pofs = dh * 32 + dw;
    int bbase = half * 128;
#pragma unroll
    for (int kc = 0; kc < 2; kc++) {
      bf16x8 af[4], bfv[2];
#pragma unroll
      for (int mi = 0; mi < 4; mi++) {
        int rowf = wr * 64 + mi * 16 + (lane & 15);
        af[mi] = *(const bf16x8*)(ABc + rowf * 128 + ((kc * 64 + kfrag) ^ ((rowf & 7) << 4)));
      }
#pragma unroll
      for (int ni = 0; ni < 2; ni++) {
        int pix = pix0[ni] + pofs;
        bfv[ni] = *(const bf16x8*)(XF + pix * 256 + ((bbase + kc * 64 + kfrag) ^ ((pix & 15) << 4)));
      }
      __builtin_amdgcn_s_setprio(1);
#pragma unroll
      for (int mi = 0; mi < 4; mi++)
#pragma unroll
        for (int ni = 0; ni < 2; ni++)
          acc[mi][ni] = __builtin_amdgcn_mfma_f32_16x16x32_bf16(
              af[mi], bfv[ni], acc[mi][ni], 0, 0, 0);
      __builtin_amdgcn_s_setprio(0);
    }
    // next A-tile was issued a full compute-phase ago from hot L2 -> wait is cheap
    asm volatile("s_waitcnt vmcnt(0)" ::: "memory");
    __builtin_amdgcn_s_barrier();
  }

  // ---- epilogue: fused norms, direct stores (16-lane x 4B = 64B segments) ----
#pragma unroll
  for (int ni = 0; ni < 2; ni++) {
    int cc = wc * 32 + ni * 16 + (lane & 15);
    if (cc < BLT) {
      float xn = xn_s[cc];
      float* ob = out + (size_t)n * (F_OUT * P_SP) + p0 + cc;
#pragma unroll
      for (int mi = 0; mi < 4; mi++) {
        int f0 = wr * 64 + mi * 16 + (lane >> 4) * 4;
#pragma unroll
        for (int r2 = 0; r2 < 4; r2++) {
          int f = f0 + r2;
          ob[f * P_SP] = acc[mi][ni][r2] - wn_s[f] - xn;
        }
      }
    }
  }
}

// ---------------------------------------------------------------------------
extern "C" void kernel_launch(void* const* d_in, const int* in_sizes, int n_in,
                              void* d_out, int out_size, void* d_ws, size_t ws_size,
                              hipStream_t stream) {
  const float* x = (const float*)d_in[0];
  const float* W = (const float*)d_in[1];
  float* out = (float*)d_out;

  char* ws = (char*)d_ws;
  unsigned short* Wbf = (unsigned short*)(ws);       // 294,912 B
  float* wnorm = (float*)(ws + 294912);              //     512 B

  prep_w_kernel<<<F_OUT, 256, 0, stream>>>(W, Wbf, wnorm);
  adder_fused_kernel<<<NBLK, 256, 0, stream>>>(x, Wbf, wnorm, out);
}